// Round 6
// baseline (678.048 us; speedup 1.0000x reference)
//
#include <hip/hip_runtime.h>

typedef unsigned short u16;
typedef short bf16x8 __attribute__((ext_vector_type(8)));
typedef float f32x4 __attribute__((ext_vector_type(4)));

#define T_  2048
#define C_  1024
#define NH_ 16
#define HD_ 64

__device__ __forceinline__ u16 f2bf(float f) {  // RNE float->bf16
  union { float f; unsigned u; } x; x.f = f;
  unsigned r = x.u + 0x7fffu + ((x.u >> 16) & 1u);
  return (u16)(r >> 16);
}

// ---------------------------------------------------------------------------
// x slice (f32) -> bf16
// ---------------------------------------------------------------------------
__global__ __launch_bounds__(256) void convert_x(const float* __restrict__ in,
                                                 u16* __restrict__ out, int n) {
  int i = (blockIdx.x * 256 + threadIdx.x) * 8;
  if (i >= n) return;
  float4 a = *(const float4*)(in + i);
  float4 b = *(const float4*)(in + i + 4);
  u16 t[8] = {f2bf(a.x), f2bf(a.y), f2bf(a.z), f2bf(a.w),
              f2bf(b.x), f2bf(b.y), f2bf(b.z), f2bf(b.w)};
  *(uint4*)(out + i) = *(const uint4*)t;
}

// ---------------------------------------------------------------------------
// Weight transpose+convert: f32 [R][Cc] -> bf16 [Cc][R]
// ---------------------------------------------------------------------------
__global__ __launch_bounds__(256) void transpose_w(const float* __restrict__ in,
                                                   u16* __restrict__ out,
                                                   int R, int Cc) {
  int r0 = blockIdx.x * 64, c0 = blockIdx.y * 64;
  __shared__ __attribute__((aligned(16))) u16 tile[64][72];
  int tid = threadIdx.x;
#pragma unroll
  for (int it = 0; it < 4; ++it) {
    int chunk = it * 256 + tid;          // 0..1023
    int row = chunk >> 4, c4 = chunk & 15;
    float4 v = *(const float4*)(in + (size_t)(r0 + row) * Cc + c0 + c4 * 4);
    tile[row][c4 * 4 + 0] = f2bf(v.x);
    tile[row][c4 * 4 + 1] = f2bf(v.y);
    tile[row][c4 * 4 + 2] = f2bf(v.z);
    tile[row][c4 * 4 + 3] = f2bf(v.w);
  }
  __syncthreads();
#pragma unroll
  for (int it = 0; it < 2; ++it) {
    int chunk = it * 256 + tid;
    int row = chunk >> 3, c8 = chunk & 7;
    uint4 v; u16* tv = (u16*)&v;
#pragma unroll
    for (int k = 0; k < 8; ++k) tv[k] = tile[c8 * 8 + k][row];
    *(uint4*)(out + (size_t)(c0 + row) * R + r0 + c8 * 8) = v;
  }
}

// ---------------------------------------------------------------------------
// bf16 tiled transpose (for V): in [batch][R][Cc] -> out [batch][Cc][R]
// ---------------------------------------------------------------------------
__global__ __launch_bounds__(256) void transpose_bf16(const u16* __restrict__ in,
                                                      u16* __restrict__ out,
                                                      int R, int Cc) {
  size_t bofs = (size_t)blockIdx.z * R * Cc;
  in += bofs; out += bofs;
  int r0 = blockIdx.x * 64, c0 = blockIdx.y * 64;
  __shared__ __attribute__((aligned(16))) u16 tile[64][72];
  int tid = threadIdx.x;
#pragma unroll
  for (int it = 0; it < 2; ++it) {
    int chunk = it * 256 + tid;
    int row = chunk >> 3, c8 = chunk & 7;
    uint4 v = *(const uint4*)(in + (size_t)(r0 + row) * Cc + c0 + c8 * 8);
    const u16* tv = (const u16*)&v;
#pragma unroll
    for (int k = 0; k < 8; ++k) tile[row][c8 * 8 + k] = tv[k];
  }
  __syncthreads();
#pragma unroll
  for (int it = 0; it < 2; ++it) {
    int chunk = it * 256 + tid;
    int row = chunk >> 3, c8 = chunk & 7;
    uint4 v; u16* tv = (u16*)&v;
#pragma unroll
    for (int k = 0; k < 8; ++k) tv[k] = tile[c8 * 8 + k][row];
    *(uint4*)(out + (size_t)(c0 + row) * R + r0 + c8 * 8) = v;
  }
}

// ---------------------------------------------------------------------------
// BT GEMM mainloop: 128x128 tile of A[M,K] @ Bt[N,K]^T. 4 waves 2x2, 4x4 MFMA.
// ---------------------------------------------------------------------------
__device__ __forceinline__ void gemm_bt_tile(const u16* __restrict__ A,
                                             const u16* __restrict__ Bt,
                                             int Kdim, int m0, int n0,
                                             u16* sA, u16* sB, f32x4 acc[4][4]) {
  int tid = threadIdx.x;
  int w = tid >> 6, l = tid & 63, li = l & 15, quad = l >> 4;
  int wm = (w >> 1) * 64, wn = (w & 1) * 64;
  f32x4 zero = {0.f, 0.f, 0.f, 0.f};
#pragma unroll
  for (int i = 0; i < 4; ++i)
#pragma unroll
    for (int j = 0; j < 4; ++j) acc[i][j] = zero;

  for (int k0 = 0; k0 < Kdim; k0 += 32) {
#pragma unroll
    for (int r = 0; r < 2; ++r) {
      int chunk = r * 256 + tid;
      int row = chunk >> 2, c8 = chunk & 3;
      uint4 va = *(const uint4*)(A  + (size_t)(m0 + row) * Kdim + k0 + c8 * 8);
      uint4 vb = *(const uint4*)(Bt + (size_t)(n0 + row) * Kdim + k0 + c8 * 8);
      *(uint4*)(sA + chunk * 8) = va;
      *(uint4*)(sB + chunk * 8) = vb;
    }
    __syncthreads();
    bf16x8 af[4], bfr[4];
#pragma unroll
    for (int i = 0; i < 4; ++i)
      af[i] = *(const bf16x8*)(sA + (wm + i * 16 + li) * 32 + quad * 8);
#pragma unroll
    for (int j = 0; j < 4; ++j)
      bfr[j] = *(const bf16x8*)(sB + (wn + j * 16 + li) * 32 + quad * 8);
#pragma unroll
    for (int i = 0; i < 4; ++i)
#pragma unroll
      for (int j = 0; j < 4; ++j)
        acc[i][j] = __builtin_amdgcn_mfma_f32_16x16x32_bf16(af[i], bfr[j], acc[i][j], 0, 0, 0);
    __syncthreads();
  }
}

// QKV GEMM one batch: X[2048,1024] @ watT[3072,1024]^T -> Q,K,V [h,t,d] bf16
__global__ __launch_bounds__(256) void gemm_qkv_b(const u16* __restrict__ X,
                                                  const u16* __restrict__ WT,
                                                  u16* __restrict__ Qb,
                                                  u16* __restrict__ Kb,
                                                  u16* __restrict__ Vb) {
  __shared__ __attribute__((aligned(16))) u16 sA[128 * 32];
  __shared__ __attribute__((aligned(16))) u16 sB[128 * 32];
  f32x4 acc[4][4];
  int m0 = blockIdx.x * 128, n0 = blockIdx.y * 128;
  gemm_bt_tile(X, WT, C_, m0, n0, sA, sB, acc);

  int tid = threadIdx.x;
  int w = tid >> 6, l = tid & 63, li = l & 15, quad = l >> 4;
  int wm = (w >> 1) * 64, wn = (w & 1) * 64;
#pragma unroll
  for (int i = 0; i < 4; ++i)
#pragma unroll
    for (int j = 0; j < 4; ++j)
#pragma unroll
      for (int r = 0; r < 4; ++r) {
        int t = m0 + wm + i * 16 + quad * 4 + r;
        int n = n0 + wn + j * 16 + li;
        int which = n >> 10, cc = n & (C_ - 1);
        int h = cc >> 6, d = cc & (HD_ - 1);
        u16* dst = (which == 0) ? Qb : ((which == 1) ? Kb : Vb);
        dst[((size_t)h * T_ + t) * HD_ + d] = f2bf(acc[i][j][r]);
      }
}

// Proj GEMM one batch: Y[2048,1024] @ wprojT[1024,1024]^T -> Out f32 [2048,1024]
__global__ __launch_bounds__(256) void gemm_proj_b(const u16* __restrict__ Y,
                                                   const u16* __restrict__ WT,
                                                   float* __restrict__ Out) {
  __shared__ __attribute__((aligned(16))) u16 sA[128 * 32];
  __shared__ __attribute__((aligned(16))) u16 sB[128 * 32];
  f32x4 acc[4][4];
  int m0 = blockIdx.x * 128, n0 = blockIdx.y * 128;
  gemm_bt_tile(Y, WT, C_, m0, n0, sA, sB, acc);

  int tid = threadIdx.x;
  int w = tid >> 6, l = tid & 63, li = l & 15, quad = l >> 4;
  int wm = (w >> 1) * 64, wn = (w & 1) * 64;
#pragma unroll
  for (int i = 0; i < 4; ++i)
#pragma unroll
    for (int j = 0; j < 4; ++j)
#pragma unroll
      for (int r = 0; r < 4; ++r) {
        int m = m0 + wm + i * 16 + quad * 4 + r;
        int n = n0 + wn + j * 16 + li;
        Out[(size_t)m * C_ + n] = acc[i][j][r];   // f32 output (the fix)
      }
}

// ---------------------------------------------------------------------------
// Flash attention, one batch: grid (32 q-tiles, 16 heads). 64 q-rows/block,
// 4 waves x 16 rows. K [h,t,d]; V^T [h,d,t]. Online softmax; P via LDS.
// ---------------------------------------------------------------------------
__global__ __launch_bounds__(256) void attn_b(const u16* __restrict__ Q,
                                              const u16* __restrict__ K,
                                              const u16* __restrict__ Vt,
                                              u16* __restrict__ Y) {
  int qt = (gridDim.x - 1) - blockIdx.x;
  int h = blockIdx.y;
  int tid = threadIdx.x;
  int w = tid >> 6, l = tid & 63, li = l & 15, quad = l >> 4;
  int q0 = qt * 64;

  __shared__ __attribute__((aligned(16))) u16 sQ[64 * 64];
  __shared__ __attribute__((aligned(16))) u16 sK[64 * 64];
  __shared__ __attribute__((aligned(16))) u16 sV[64 * 64];
  __shared__ __attribute__((aligned(16))) u16 sP[64 * 72];

  const u16* qptr = Q + ((size_t)h * T_ + q0) * HD_;
#pragma unroll
  for (int r = 0; r < 2; ++r) {
    int chunk = r * 256 + tid;
    *(uint4*)(sQ + chunk * 8) = *(const uint4*)(qptr + chunk * 8);
  }
  __syncthreads();

  bf16x8 qf0, qf1;
  {
    int row = 16 * w + li;
    qf0 = *(const bf16x8*)(sQ + row * 64 + quad * 8);
    qf1 = *(const bf16x8*)(sQ + row * 64 + 32 + quad * 8);
  }

  f32x4 o[4];
  f32x4 zero = {0.f, 0.f, 0.f, 0.f};
#pragma unroll
  for (int j = 0; j < 4; ++j) o[j] = zero;
  float mrow[4] = {-1e30f, -1e30f, -1e30f, -1e30f};
  float lrow[4] = {0.f, 0.f, 0.f, 0.f};
  const float csc = 0.125f * 1.44269504088896f;  // 1/sqrt(64) * log2(e)

  for (int kvt = 0; kvt <= qt; ++kvt) {
    int kv0 = kvt * 64;
    const u16* kptr = K + ((size_t)h * T_ + kv0) * HD_;
    const u16* vptr = Vt + (size_t)h * HD_ * T_ + kv0;
#pragma unroll
    for (int r = 0; r < 2; ++r) {
      int chunk = r * 256 + tid;
      uint4 vk = *(const uint4*)(kptr + chunk * 8);
      int d = chunk >> 3, c8 = chunk & 7;
      uint4 vv = *(const uint4*)(vptr + (size_t)d * T_ + c8 * 8);
      *(uint4*)(sK + chunk * 8) = vk;
      *(uint4*)(sV + chunk * 8) = vv;
    }
    __syncthreads();

    f32x4 s[4];
#pragma unroll
    for (int j = 0; j < 4; ++j) {
      int rowk = j * 16 + li;
      bf16x8 kf0 = *(const bf16x8*)(sK + rowk * 64 + quad * 8);
      bf16x8 kf1 = *(const bf16x8*)(sK + rowk * 64 + 32 + quad * 8);
      f32x4 z = zero;
      z = __builtin_amdgcn_mfma_f32_16x16x32_bf16(qf0, kf0, z, 0, 0, 0);
      z = __builtin_amdgcn_mfma_f32_16x16x32_bf16(qf1, kf1, z, 0, 0, 0);
      s[j] = z;
    }

    if (kvt == qt) {
#pragma unroll
      for (int j = 0; j < 4; ++j)
#pragma unroll
        for (int r = 0; r < 4; ++r) {
          int qrow = 16 * w + quad * 4 + r;
          int kcol = j * 16 + li;
          if (kcol > qrow) s[j][r] = -1e30f;
        }
    }

    float mnew[4], alpha[4];
#pragma unroll
    for (int r = 0; r < 4; ++r) {
      float v = fmaxf(fmaxf(s[0][r], s[1][r]), fmaxf(s[2][r], s[3][r]));
#pragma unroll
      for (int off = 1; off < 16; off <<= 1) v = fmaxf(v, __shfl_xor(v, off, 16));
      mnew[r] = fmaxf(mrow[r], v);
      alpha[r] = exp2f((mrow[r] - mnew[r]) * csc);
      mrow[r] = mnew[r];
    }
#pragma unroll
    for (int j = 0; j < 4; ++j)
#pragma unroll
      for (int r = 0; r < 4; ++r)
        s[j][r] = exp2f((s[j][r] - mnew[r]) * csc);
#pragma unroll
    for (int r = 0; r < 4; ++r) {
      float sum = s[0][r] + s[1][r] + s[2][r] + s[3][r];
#pragma unroll
      for (int off = 1; off < 16; off <<= 1) sum += __shfl_xor(sum, off, 16);
      lrow[r] = lrow[r] * alpha[r] + sum;
#pragma unroll
      for (int j = 0; j < 4; ++j) o[j][r] = o[j][r] * alpha[r];
    }

#pragma unroll
    for (int j = 0; j < 4; ++j)
#pragma unroll
      for (int r = 0; r < 4; ++r)
        sP[(16 * w + quad * 4 + r) * 72 + j * 16 + li] = f2bf(s[j][r]);
    __syncthreads();

    int prow = 16 * w + li;
    bf16x8 pf0 = *(const bf16x8*)(sP + prow * 72 + quad * 8);
    bf16x8 pf1 = *(const bf16x8*)(sP + prow * 72 + 32 + quad * 8);
#pragma unroll
    for (int j = 0; j < 4; ++j) {
      int rowv = j * 16 + li;
      bf16x8 vf0 = *(const bf16x8*)(sV + rowv * 64 + quad * 8);
      bf16x8 vf1 = *(const bf16x8*)(sV + rowv * 64 + 32 + quad * 8);
      o[j] = __builtin_amdgcn_mfma_f32_16x16x32_bf16(pf0, vf0, o[j], 0, 0, 0);
      o[j] = __builtin_amdgcn_mfma_f32_16x16x32_bf16(pf1, vf1, o[j], 0, 0, 0);
    }
    __syncthreads();
  }

  float rinv[4];
#pragma unroll
  for (int r = 0; r < 4; ++r) rinv[r] = 1.0f / fmaxf(lrow[r], 1e-20f);
#pragma unroll
  for (int j = 0; j < 4; ++j)
#pragma unroll
    for (int r = 0; r < 4; ++r) {
      int t = q0 + 16 * w + quad * 4 + r;
      int d = j * 16 + li;
      Y[(size_t)t * C_ + h * HD_ + d] = f2bf(o[j][r] * rinv[r]);
    }
}

// ---------------------------------------------------------------------------
extern "C" void kernel_launch(void* const* d_in, const int* in_sizes, int n_in,
                              void* d_out, int out_size, void* d_ws, size_t ws_size,
                              hipStream_t stream) {
  (void)in_sizes; (void)n_in; (void)out_size; (void)ws_size;
  const float* x      = (const float*)d_in[0];   // [B,T,C] f32
  const float* w_attn = (const float*)d_in[1];   // [C,3C]  f32
  const float* w_proj = (const float*)d_in[2];   // [C,C]   f32
  float* out = (float*)d_out;                    // [B,T,C] f32  <-- the fix

  // ws (u16 elems): 3.15M+1.05M+2.10M+4*2.10M+2.10M = 16.8M = 33.6 MB
  u16* watT   = (u16*)d_ws;                       // [3072][1024]
  u16* wprojT = watT   + (size_t)3 * C_ * C_;     // [1024][1024]
  u16* xbf    = wprojT + (size_t)C_ * C_;         // [2048][1024] per batch
  u16* qb     = xbf    + (size_t)T_ * C_;         // [16][2048][64]
  u16* kb     = qb     + (size_t)NH_ * T_ * HD_;
  u16* vb     = kb     + (size_t)NH_ * T_ * HD_;
  u16* vtb    = vb     + (size_t)NH_ * T_ * HD_;
  u16* yb     = vtb    + (size_t)NH_ * T_ * HD_;  // [2048][1024]

  transpose_w<<<dim3(16, 48), 256, 0, stream>>>(w_attn, watT, C_, 3 * C_);
  transpose_w<<<dim3(16, 16), 256, 0, stream>>>(w_proj, wprojT, C_, C_);

  for (int b = 0; b < 4; ++b) {
    const float* xb = x + (size_t)b * T_ * C_;
    float* outb = out + (size_t)b * T_ * C_;
    convert_x<<<dim3(1024), 256, 0, stream>>>(xb, xbf, T_ * C_);
    gemm_qkv_b<<<dim3(16, 24), 256, 0, stream>>>(xbf, watT, qb, kb, vb);
    transpose_bf16<<<dim3(32, 1, NH_), 256, 0, stream>>>(vb, vtb, T_, HD_);
    attn_b<<<dim3(32, NH_), 256, 0, stream>>>(qb, kb, vtb, yb);
    gemm_proj_b<<<dim3(16, 8), 256, 0, stream>>>(yb, wprojT, outb);
  }
}

// Round 7
// 431.295 us; speedup vs baseline: 1.5721x; 1.5721x over previous
//
#include <hip/hip_runtime.h>

typedef unsigned short u16;
typedef short bf16x8 __attribute__((ext_vector_type(8)));
typedef float f32x4 __attribute__((ext_vector_type(4)));

#define B_  4
#define T_  2048
#define C_  1024
#define NH_ 16
#define HD_ 64

// async global->LDS, 16B/lane; LDS dest = wave-uniform base + lane*16.
__device__ __forceinline__ void gload16(const u16* g, u16* lds) {
  __builtin_amdgcn_global_load_lds(
      (const __attribute__((address_space(1))) void*)g,
      (__attribute__((address_space(3))) void*)lds, 16, 0, 0);
}

__device__ __forceinline__ u16 f2bf(float f) {  // RNE float->bf16
  union { float f; unsigned u; } x; x.f = f;
  unsigned r = x.u + 0x7fffu + ((x.u >> 16) & 1u);
  return (u16)(r >> 16);
}

// ---------------------------------------------------------------------------
// x (f32, all batches) -> bf16
// ---------------------------------------------------------------------------
__global__ __launch_bounds__(256) void convert_x(const float* __restrict__ in,
                                                 u16* __restrict__ out) {
  int i = (blockIdx.x * 256 + threadIdx.x) * 8;
  float4 a = *(const float4*)(in + i);
  float4 b = *(const float4*)(in + i + 4);
  u16 t[8] = {f2bf(a.x), f2bf(a.y), f2bf(a.z), f2bf(a.w),
              f2bf(b.x), f2bf(b.y), f2bf(b.z), f2bf(b.w)};
  *(uint4*)(out + i) = *(const uint4*)t;
}

// ---------------------------------------------------------------------------
// Weight transpose+convert: f32 [R][Cc] -> bf16 [Cc][R]
// ---------------------------------------------------------------------------
__global__ __launch_bounds__(256) void transpose_w(const float* __restrict__ in,
                                                   u16* __restrict__ out,
                                                   int R, int Cc) {
  int r0 = blockIdx.x * 64, c0 = blockIdx.y * 64;
  __shared__ __attribute__((aligned(16))) u16 tile[64][72];
  int tid = threadIdx.x;
#pragma unroll
  for (int it = 0; it < 4; ++it) {
    int chunk = it * 256 + tid;          // 0..1023
    int row = chunk >> 4, c4 = chunk & 15;
    float4 v = *(const float4*)(in + (size_t)(r0 + row) * Cc + c0 + c4 * 4);
    tile[row][c4 * 4 + 0] = f2bf(v.x);
    tile[row][c4 * 4 + 1] = f2bf(v.y);
    tile[row][c4 * 4 + 2] = f2bf(v.z);
    tile[row][c4 * 4 + 3] = f2bf(v.w);
  }
  __syncthreads();
#pragma unroll
  for (int it = 0; it < 2; ++it) {
    int chunk = it * 256 + tid;
    int row = chunk >> 3, c8 = chunk & 7;
    uint4 v; u16* tv = (u16*)&v;
#pragma unroll
    for (int k = 0; k < 8; ++k) tv[k] = tile[c8 * 8 + k][row];
    *(uint4*)(out + (size_t)(c0 + row) * R + r0 + c8 * 8) = v;
  }
}

// ---------------------------------------------------------------------------
// m97-style async BT GEMM mainloop: 128x128 tile of A[M,K] @ Bt[N,K]^T.
// global_load_lds width-16 staging, unpadded stride-32 LDS (874 TF class).
// ---------------------------------------------------------------------------
__device__ __forceinline__ void gemm_bt_tile(const u16* __restrict__ A,
                                             const u16* __restrict__ Bt,
                                             int Kdim, int m0, int n0,
                                             u16* sA, u16* sB, f32x4 acc[4][4]) {
  int tid = threadIdx.x;
  int w = tid >> 6, l = tid & 63, li = l & 15, quad = l >> 4;
  int wm = (w >> 1) * 64, wn = (w & 1) * 64;
  f32x4 zero = {0.f, 0.f, 0.f, 0.f};
#pragma unroll
  for (int i = 0; i < 4; ++i)
#pragma unroll
    for (int j = 0; j < 4; ++j) acc[i][j] = zero;

  for (int k0 = 0; k0 < Kdim; k0 += 32) {
#pragma unroll
    for (int r = 0; r < 2; ++r) {
      int chunk = r * 256 + tid;           // 0..511, lane-contiguous per wave
      int row = chunk >> 2, c8 = chunk & 3;
      gload16(A  + (size_t)(m0 + row) * Kdim + k0 + c8 * 8, sA + chunk * 8);
      gload16(Bt + (size_t)(n0 + row) * Kdim + k0 + c8 * 8, sB + chunk * 8);
    }
    __syncthreads();
    bf16x8 af[4], bfr[4];
#pragma unroll
    for (int i = 0; i < 4; ++i)
      af[i] = *(const bf16x8*)(sA + (wm + i * 16 + li) * 32 + quad * 8);
#pragma unroll
    for (int j = 0; j < 4; ++j)
      bfr[j] = *(const bf16x8*)(sB + (wn + j * 16 + li) * 32 + quad * 8);
#pragma unroll
    for (int i = 0; i < 4; ++i)
#pragma unroll
      for (int j = 0; j < 4; ++j)
        acc[i][j] = __builtin_amdgcn_mfma_f32_16x16x32_bf16(af[i], bfr[j], acc[i][j], 0, 0, 0);
    __syncthreads();
  }
}

// ---------------------------------------------------------------------------
// QKV GEMM, all batches: X[8192,1024] @ watT[3072,1024]^T.
// Epilogue scatters Q,K as [b,h,t,d] and V directly transposed [b,h,d,t]
// (vectorized 8B stores: 4 consecutive t per lane).
// ---------------------------------------------------------------------------
__global__ __launch_bounds__(256) void gemm_qkv(const u16* __restrict__ X,
                                                const u16* __restrict__ WT,
                                                u16* __restrict__ Qb,
                                                u16* __restrict__ Kb,
                                                u16* __restrict__ Vt) {
  __shared__ __attribute__((aligned(16))) u16 sA[128 * 32];
  __shared__ __attribute__((aligned(16))) u16 sB[128 * 32];
  f32x4 acc[4][4];
  int m0 = blockIdx.x * 128, n0 = blockIdx.y * 128;
  gemm_bt_tile(X, WT, C_, m0, n0, sA, sB, acc);

  int tid = threadIdx.x;
  int w = tid >> 6, l = tid & 63, li = l & 15, quad = l >> 4;
  int wm = (w >> 1) * 64, wn = (w & 1) * 64;
#pragma unroll
  for (int i = 0; i < 4; ++i)
#pragma unroll
    for (int j = 0; j < 4; ++j) {
      int n = n0 + wn + j * 16 + li;
      int which = n >> 10, cc = n & (C_ - 1);
      int h = cc >> 6, d = cc & (HD_ - 1);
      int mb = m0 + wm + i * 16 + quad * 4;
      int b = mb >> 11, t0 = mb & (T_ - 1);
      if (which == 2) {
        u16 tv[4] = {f2bf(acc[i][j][0]), f2bf(acc[i][j][1]),
                     f2bf(acc[i][j][2]), f2bf(acc[i][j][3])};
        *(uint2*)(Vt + ((size_t)(b * NH_ + h) * HD_ + d) * T_ + t0) = *(const uint2*)tv;
      } else {
        u16* dst = (which == 0) ? Qb : Kb;
#pragma unroll
        for (int r = 0; r < 4; ++r)
          dst[((size_t)(b * NH_ + h) * T_ + t0 + r) * HD_ + d] = f2bf(acc[i][j][r]);
      }
    }
}

// ---------------------------------------------------------------------------
// Proj GEMM, all batches: Y[8192,1024] @ wprojT[1024,1024]^T -> f32 out
// ---------------------------------------------------------------------------
__global__ __launch_bounds__(256) void gemm_proj(const u16* __restrict__ Y,
                                                 const u16* __restrict__ WT,
                                                 float* __restrict__ Out) {
  __shared__ __attribute__((aligned(16))) u16 sA[128 * 32];
  __shared__ __attribute__((aligned(16))) u16 sB[128 * 32];
  f32x4 acc[4][4];
  int m0 = blockIdx.x * 128, n0 = blockIdx.y * 128;
  gemm_bt_tile(Y, WT, C_, m0, n0, sA, sB, acc);

  int tid = threadIdx.x;
  int w = tid >> 6, l = tid & 63, li = l & 15, quad = l >> 4;
  int wm = (w >> 1) * 64, wn = (w & 1) * 64;
#pragma unroll
  for (int i = 0; i < 4; ++i)
#pragma unroll
    for (int j = 0; j < 4; ++j)
#pragma unroll
      for (int r = 0; r < 4; ++r) {
        int m = m0 + wm + i * 16 + quad * 4 + r;
        int n = n0 + wn + j * 16 + li;
        Out[(size_t)m * C_ + n] = acc[i][j][r];
      }
}

// ---------------------------------------------------------------------------
// Flash attention, all batches: grid (32 q-tiles, 64 bh). 64 q-rows/block,
// 4 waves x 16 rows. K [bh,t,d]; V^T [bh,d,t]. Padded LDS (stride 72) kills
// the 16-way bank conflicts of r6; sync staging.
// ---------------------------------------------------------------------------
__global__ __launch_bounds__(256) void attn_k(const u16* __restrict__ Q,
                                              const u16* __restrict__ K,
                                              const u16* __restrict__ Vt,
                                              u16* __restrict__ Y) {
  int qt = (gridDim.x - 1) - blockIdx.x;   // heavy blocks first
  int bh = blockIdx.y;
  int tid = threadIdx.x;
  int w = tid >> 6, l = tid & 63, li = l & 15, quad = l >> 4;
  int q0 = qt * 64;

  __shared__ __attribute__((aligned(16))) u16 sQ[64 * 72];
  __shared__ __attribute__((aligned(16))) u16 sK[64 * 72];
  __shared__ __attribute__((aligned(16))) u16 sV[64 * 72];   // Vt tile [d][t]
  __shared__ __attribute__((aligned(16))) u16 sP[64 * 72];

  const u16* qptr = Q + ((size_t)bh * T_ + q0) * HD_;
#pragma unroll
  for (int r = 0; r < 2; ++r) {
    int chunk = r * 256 + tid;
    int row = chunk >> 3, c8 = chunk & 7;
    *(uint4*)(sQ + row * 72 + c8 * 8) = *(const uint4*)(qptr + chunk * 8);
  }
  __syncthreads();

  bf16x8 qf0, qf1;
  {
    int row = 16 * w + li;
    qf0 = *(const bf16x8*)(sQ + row * 72 + quad * 8);
    qf1 = *(const bf16x8*)(sQ + row * 72 + 32 + quad * 8);
  }

  f32x4 o[4];
  f32x4 zero = {0.f, 0.f, 0.f, 0.f};
#pragma unroll
  for (int j = 0; j < 4; ++j) o[j] = zero;
  float mrow[4] = {-1e30f, -1e30f, -1e30f, -1e30f};
  float lrow[4] = {0.f, 0.f, 0.f, 0.f};
  const float csc = 0.125f * 1.44269504088896f;  // 1/sqrt(64) * log2(e)

  for (int kvt = 0; kvt <= qt; ++kvt) {
    int kv0 = kvt * 64;
    const u16* kptr = K + ((size_t)bh * T_ + kv0) * HD_;
    const u16* vptr = Vt + (size_t)bh * HD_ * T_ + kv0;
#pragma unroll
    for (int r = 0; r < 2; ++r) {
      int chunk = r * 256 + tid;
      int row = chunk >> 3, c8 = chunk & 7;
      uint4 vk = *(const uint4*)(kptr + chunk * 8);
      uint4 vv = *(const uint4*)(vptr + (size_t)row * T_ + c8 * 8);
      *(uint4*)(sK + row * 72 + c8 * 8) = vk;
      *(uint4*)(sV + row * 72 + c8 * 8) = vv;
    }
    __syncthreads();

    f32x4 s[4];
#pragma unroll
    for (int j = 0; j < 4; ++j) {
      int rowk = j * 16 + li;
      bf16x8 kf0 = *(const bf16x8*)(sK + rowk * 72 + quad * 8);
      bf16x8 kf1 = *(const bf16x8*)(sK + rowk * 72 + 32 + quad * 8);
      f32x4 z = zero;
      z = __builtin_amdgcn_mfma_f32_16x16x32_bf16(qf0, kf0, z, 0, 0, 0);
      z = __builtin_amdgcn_mfma_f32_16x16x32_bf16(qf1, kf1, z, 0, 0, 0);
      s[j] = z;
    }

    if (kvt == qt) {
#pragma unroll
      for (int j = 0; j < 4; ++j)
#pragma unroll
        for (int r = 0; r < 4; ++r) {
          int qrow = 16 * w + quad * 4 + r;
          int kcol = j * 16 + li;
          if (kcol > qrow) s[j][r] = -1e30f;
        }
    }

    float mnew[4], alpha[4];
#pragma unroll
    for (int r = 0; r < 4; ++r) {
      float v = fmaxf(fmaxf(s[0][r], s[1][r]), fmaxf(s[2][r], s[3][r]));
#pragma unroll
      for (int off = 1; off < 16; off <<= 1) v = fmaxf(v, __shfl_xor(v, off, 16));
      mnew[r] = fmaxf(mrow[r], v);
      alpha[r] = exp2f((mrow[r] - mnew[r]) * csc);
      mrow[r] = mnew[r];
    }
#pragma unroll
    for (int j = 0; j < 4; ++j)
#pragma unroll
      for (int r = 0; r < 4; ++r)
        s[j][r] = exp2f((s[j][r] - mnew[r]) * csc);
#pragma unroll
    for (int r = 0; r < 4; ++r) {
      float sum = s[0][r] + s[1][r] + s[2][r] + s[3][r];
#pragma unroll
      for (int off = 1; off < 16; off <<= 1) sum += __shfl_xor(sum, off, 16);
      lrow[r] = lrow[r] * alpha[r] + sum;
#pragma unroll
      for (int j = 0; j < 4; ++j) o[j][r] = o[j][r] * alpha[r];
    }

#pragma unroll
    for (int j = 0; j < 4; ++j)
#pragma unroll
      for (int r = 0; r < 4; ++r)
        sP[(16 * w + quad * 4 + r) * 72 + j * 16 + li] = f2bf(s[j][r]);
    __syncthreads();

    int prow = 16 * w + li;
    bf16x8 pf0 = *(const bf16x8*)(sP + prow * 72 + quad * 8);
    bf16x8 pf1 = *(const bf16x8*)(sP + prow * 72 + 32 + quad * 8);
#pragma unroll
    for (int j = 0; j < 4; ++j) {
      int rowv = j * 16 + li;
      bf16x8 vf0 = *(const bf16x8*)(sV + rowv * 72 + quad * 8);
      bf16x8 vf1 = *(const bf16x8*)(sV + rowv * 72 + 32 + quad * 8);
      o[j] = __builtin_amdgcn_mfma_f32_16x16x32_bf16(pf0, vf0, o[j], 0, 0, 0);
      o[j] = __builtin_amdgcn_mfma_f32_16x16x32_bf16(pf1, vf1, o[j], 0, 0, 0);
    }
    __syncthreads();
  }

  int b = bh >> 4, h = bh & (NH_ - 1);
  float rinv[4];
#pragma unroll
  for (int r = 0; r < 4; ++r) rinv[r] = 1.0f / fmaxf(lrow[r], 1e-20f);
#pragma unroll
  for (int j = 0; j < 4; ++j)
#pragma unroll
    for (int r = 0; r < 4; ++r) {
      int t = q0 + 16 * w + quad * 4 + r;
      int d = j * 16 + li;
      Y[((size_t)b * T_ + t) * C_ + h * HD_ + d] = f2bf(o[j][r] * rinv[r]);
    }
}

// ---------------------------------------------------------------------------
extern "C" void kernel_launch(void* const* d_in, const int* in_sizes, int n_in,
                              void* d_out, int out_size, void* d_ws, size_t ws_size,
                              hipStream_t stream) {
  (void)in_sizes; (void)n_in; (void)out_size; (void)ws_size;
  const float* x      = (const float*)d_in[0];   // [B,T,C] f32
  const float* w_attn = (const float*)d_in[1];   // [C,3C]  f32
  const float* w_proj = (const float*)d_in[2];   // [C,C]   f32
  float* out = (float*)d_out;                    // [B,T,C] f32

  const size_t NTOK = (size_t)B_ * T_ * C_;      // 8.39M elems
  u16* watT   = (u16*)d_ws;                      // 3.15M
  u16* wprojT = watT   + (size_t)3 * C_ * C_;    // 1.05M
  u16* xbf    = wprojT + (size_t)C_ * C_;        // 8.39M (yb overlays this)
  u16* qb     = xbf  + NTOK;                     // 8.39M [b,h,t,d]
  u16* kb     = qb   + NTOK;                     // 8.39M [b,h,t,d]
  u16* vtb    = kb   + NTOK;                     // 8.39M [b,h,d,t]
  u16* yb     = xbf;                             // overlay: xbf dead after qkv
  // total ws: 37.8M u16 = 75.5 MB

  transpose_w<<<dim3(16, 48), 256, 0, stream>>>(w_attn, watT, C_, 3 * C_);
  transpose_w<<<dim3(16, 16), 256, 0, stream>>>(w_proj, wprojT, C_, C_);
  convert_x<<<dim3(4096), 256, 0, stream>>>(x, xbf);
  gemm_qkv<<<dim3(64, 24), 256, 0, stream>>>(xbf, watT, qb, kb, vtb);
  attn_k<<<dim3(32, 64), 256, 0, stream>>>(qb, kb, vtb, yb);
  gemm_proj<<<dim3(64, 8), 256, 0, stream>>>(yb, wprojT, out);
}